// Round 4
// baseline (18.074 us; speedup 1.0000x reference)
//
#include <hip/hip_runtime.h>
#include <hip/hip_bf16.h>

#define T_LEN 4096
#define NLAG  8

typedef __attribute__((ext_vector_type(8))) short short8;
typedef __attribute__((ext_vector_type(4))) float f32x4;

static __device__ __forceinline__ unsigned short f2bf(float f) {
  __hip_bfloat16 h = __float2bfloat16(f);
  return *reinterpret_cast<unsigned short*>(&h);
}

// ---- prep: kt[j][r][s] = k_{j*128+r-s} (bf16), k_d = Re(c^H b lam^d), k_{d<0}=0.
// One wave per lag d; butterfly leaves the full sum in ALL lanes, lane r
// scatters its row's diagonal entries. d in [-127, 960] covers every kt entry.
__global__ __launch_bounds__(256) void prep(
    const float* __restrict__ rho, const float* __restrict__ theta,
    const float* __restrict__ br, const float* __restrict__ bi,
    const float* __restrict__ cr, const float* __restrict__ ci,
    unsigned short* __restrict__ kt) {
  const int lane = threadIdx.x & 63;
  const int wid = blockIdx.x * 4 + (threadIdx.x >> 6);
  const int d = wid - 127;
  float v = 0.f;
  if (d >= 0) {                       // wave-uniform
    const float logr = -log1pf(expf(rho[lane]));
    const float rd = expf((float)d * logr);
    const float ang = theta[lane] * (float)d;
    const float brv = br[lane], biv = bi[lane];
    const float crv = cr[lane], civ = ci[lane];
    const float gr = crv * brv + civ * biv;
    const float gi = crv * biv - civ * brv;
    v = rd * (gr * cosf(ang) - gi * sinf(ang));
#pragma unroll
    for (int off = 1; off < 64; off <<= 1) v += __shfl_xor(v, off);
  }
  const unsigned short kv = f2bf(v);
#pragma unroll
  for (int j = 0; j < NLAG; ++j) {
    const int delta = d - j * 128;
    if (delta >= -127 && delta <= 63) {
      const int s = lane - delta;
      if (s >= 0 && s < 128) kt[(j * 64 + lane) * 128 + s] = kv;
    }
  }
}

#define CVT8(dst, va, vb) {                                                       \
    short8 _v;                                                                    \
    _v[0] = (short)f2bf((va).x); _v[1] = (short)f2bf((va).y);                     \
    _v[2] = (short)f2bf((va).z); _v[3] = (short)f2bf((va).w);                     \
    _v[4] = (short)f2bf((vb).x); _v[5] = (short)f2bf((vb).y);                     \
    _v[6] = (short)f2bf((vb).z); _v[7] = (short)f2bf((vb).w);                     \
    *reinterpret_cast<short8*>(dst) = _v; }

// ---- banded Toeplitz GEMM, 8 waves (ks-split), reg-staged f32 u -> bf16 LDS ----
__global__ __launch_bounds__(512) void conv_gemm(
    const float* __restrict__ u, const unsigned short* __restrict__ kt,
    float* __restrict__ out) {
  __shared__ __align__(16) unsigned short smem[32768];  // 2 bufs x (A 16KB + B 16KB)
  const int tid = threadIdx.x;
  const int lane = tid & 63;
  const int w = tid >> 6;              // 0..7
  const int wq = w & 3, kh = w >> 2;   // kh: ks-half
  const int wm = wq >> 1, wn = wq & 1;

  const int bid = blockIdx.x;          // 256 % 8 == 0 -> bijective XCD swizzle
  const int swz = (bid & 7) * 32 + (bid >> 3);
  const int t0 = (swz & 63) * 64;
  const int b0 = (swz >> 6) * 64;

  // A staging: thread handles chunks tid and tid+512 of the 64x128 tile
  const int c1 = tid + 512;
  const int r0 = tid >> 4, g0 = (tid & 15) * 8;
  const int r1 = c1 >> 4,  g1 = (c1 & 15) * 8;
  const float* ur0 = u + (size_t)(b0 + r0) * T_LEN;
  const float* ur1 = u + (size_t)(b0 + r1) * T_LEN;
  const int wo0 = r0 * 128 + (g0 ^ ((r0 & 7) << 3));
  const int wo1 = r1 * 128 + (g1 ^ ((r1 & 7) << 3));

  const int lrow = lane >> 4, lc16 = lane & 15;
  const float4 z4 = make_float4(0.f, 0.f, 0.f, 0.f);
  float4 a0, a1, a2, a3;
  f32x4 acc[2][2] = {};

#define ISSUEA(j) {                                                               \
    int gg = t0 - (j) * 128 + g0;                                                 \
    if ((unsigned)gg < 4096u) {                                                   \
      const float4* p = reinterpret_cast<const float4*>(ur0 + gg);                \
      a0 = p[0]; a1 = p[1];                                                       \
    } else { a0 = z4; a1 = z4; }                                                  \
    gg = t0 - (j) * 128 + g1;                                                     \
    if ((unsigned)gg < 4096u) {                                                   \
      const float4* p = reinterpret_cast<const float4*>(ur1 + gg);                \
      a2 = p[0]; a3 = p[1];                                                       \
    } else { a2 = z4; a3 = z4; } }

#define WRITEA(buf) {                                                             \
    unsigned short* Ab = &smem[(buf) * 16384];                                    \
    CVT8(Ab + wo0, a0, a1);                                                       \
    CVT8(Ab + wo1, a2, a3); }

#define GLOADB(buf, j) {                                                          \
    _Pragma("unroll") for (int i_ = 0; i_ < 2; ++i_) {                            \
      const int ii_ = w * 2 + i_;                                                 \
      const int r_ = ii_ * 4 + lrow;                                              \
      const int le_ = (lc16 * 8) ^ ((r_ & 7) << 3);                               \
      __builtin_amdgcn_global_load_lds(                                           \
          (const __attribute__((address_space(1))) void*)(kt + (j) * 8192 +       \
              r_ * 128 + le_),                                                    \
          (__attribute__((address_space(3))) void*)&smem[(buf) * 16384 + 8192 +   \
              ii_ * 512],                                                         \
          16, 0, 0); } }

#define COMPUTE(buf) {                                                            \
    const unsigned short* A  = &smem[(buf) * 16384];                              \
    const unsigned short* Bt = A + 8192;                                          \
    _Pragma("unroll") for (int ksl = 0; ksl < 2; ++ksl) {                         \
      const int ks = kh * 2 + ksl;                                                \
      short8 af[2], bf[2];                                                        \
      _Pragma("unroll") for (int ft = 0; ft < 2; ++ft) {                          \
        const int r = wm * 32 + ft * 16 + lc16;                                   \
        const int pe = (ks * 32 + lrow * 8) ^ ((r & 7) << 3);                     \
        af[ft] = *reinterpret_cast<const short8*>(&A[r * 128 + pe]); }            \
      _Pragma("unroll") for (int fn = 0; fn < 2; ++fn) {                          \
        const int r = wn * 32 + fn * 16 + lc16;                                   \
        const int pe = (ks * 32 + lrow * 8) ^ ((r & 7) << 3);                     \
        bf[fn] = *reinterpret_cast<const short8*>(&Bt[r * 128 + pe]); }           \
      _Pragma("unroll") for (int ft = 0; ft < 2; ++ft)                            \
        _Pragma("unroll") for (int fn = 0; fn < 2; ++fn)                          \
          acc[ft][fn] = __builtin_amdgcn_mfma_f32_16x16x32_bf16(                  \
              af[ft], bf[fn], acc[ft][fn], 0, 0, 0); } }

  // prologue: buf0 staged; A(1)/B(1) issued post-barrier so they fly over compute(0)
  ISSUEA(0); GLOADB(0, 0);
  WRITEA(0);
  __syncthreads();          // implicit vmcnt(0): B(0) landed
  ISSUEA(1); GLOADB(1, 1);

#pragma unroll
  for (int j = 0; j < NLAG; ++j) {
    COMPUTE(j & 1);
    if (j < NLAG - 1) {
      WRITEA((j + 1) & 1);                         // A(j+1) regs -> LDS
      __syncthreads();                             // drains B(j+1); buf[(j+1)&1] ready
      if (j + 2 < NLAG) { ISSUEA(j + 2); GLOADB(j & 1, j + 2); }
    }
  }

  // epilogue: kh=1 dumps acc into LDS (aliases buf0.A, last read at j=6), kh=0 reduces
  float* red = reinterpret_cast<float*>(smem);     // 4 wq x 16 e x 64 lanes = 16KB
  if (kh == 1) {
#pragma unroll
    for (int ft = 0; ft < 2; ++ft)
#pragma unroll
      for (int fn = 0; fn < 2; ++fn)
#pragma unroll
        for (int rg = 0; rg < 4; ++rg)
          red[((wq * 4 + ft * 2 + fn) * 4 + rg) * 64 + lane] = acc[ft][fn][rg];
  }
  __syncthreads();
  if (kh == 0) {
#pragma unroll
    for (int ft = 0; ft < 2; ++ft)
#pragma unroll
      for (int fn = 0; fn < 2; ++fn)
#pragma unroll
        for (int rg = 0; rg < 4; ++rg) {
          const float s = acc[ft][fn][rg] +
              red[((wq * 4 + ft * 2 + fn) * 4 + rg) * 64 + lane];
          const int row = b0 + wm * 32 + ft * 16 + lrow * 4 + rg;
          const int col = t0 + wn * 32 + fn * 16 + lc16;
          out[(size_t)row * T_LEN + col] = s;
        }
  }
#undef ISSUEA
#undef WRITEA
#undef GLOADB
#undef COMPUTE
}

extern "C" void kernel_launch(void* const* d_in, const int* in_sizes, int n_in,
                              void* d_out, int out_size, void* d_ws, size_t ws_size,
                              hipStream_t stream) {
  const float* u     = (const float*)d_in[0];
  const float* rho   = (const float*)d_in[1];
  const float* theta = (const float*)d_in[2];
  const float* br    = (const float*)d_in[3];
  const float* bi    = (const float*)d_in[4];
  const float* cr    = (const float*)d_in[5];
  const float* ci    = (const float*)d_in[6];
  float* out = (float*)d_out;

  unsigned short* kt = (unsigned short*)d_ws;   // 8*64*128 bf16 = 128KB

  prep<<<272, 256, 0, stream>>>(rho, theta, br, bi, cr, ci, kt);
  conv_gemm<<<256, 512, 0, stream>>>(u, kt, out);
}